// Round 5
// baseline (173.250 us; speedup 1.0000x reference)
//
#include <hip/hip_runtime.h>
#include <cstdint>

#define NB 8
#define NBOX 8732
#define NCL 21
#define NCM1 20
#define LASTD 102
#define CONF_TH 0.5f
#define IOU_TH 0.45f
#define TOPK 200
#define MAXOUT 400
#define NTASK (NB * NCM1)
#define THREADS 1024
#define NW 16
#define NIT 9          // ceil(8732/1024)
#define NBIN 2048
#define KPAD 8768      // 64*137 >= NBOX: counting-sorted keys always fit
#define NBATCH (KPAD / 64)

struct SM {
    float selx[MAXOUT], sely[MAXOUT], selz[MAXOUT], selw[MAXOUT], selA[MAXOUT];
    uint64_t selkey[MAXOUT];
    uint64_t keys[KPAD];          // 70.1 KB (reused as topk merge buffer)
    uint64_t imask[2][NW][64];    // 16 KB, double-buffered by batch parity
    int hist[NBIN], binstart[NBIN];
    int wavetot[NW];
    unsigned long long supA[2];   // ext-suppression ballots, double-buffered
    int Mshare, nselshare, prevNshare, doneflag, lastflag;
};

// IoU(>thr) with precomputed areas; explicit RN ops match the host fp32
// reference bit-for-bit (union = (aA+bA)-inter, then fdiv, strict >).
// Zero-area (invalid) operands yield false exactly like the reference's
// where(union>0, inter/union, 0) path.
__device__ __forceinline__ bool iou_gt_pre(float ax, float ay, float az, float aw, float aA,
                                           float bx, float by, float bz, float bw, float bA) {
    float x1 = fmaxf(ax, bx), y1 = fmaxf(ay, by);
    float x2 = fminf(az, bz), y2 = fminf(aw, bw);
    float iw = fmaxf(__fsub_rn(x2, x1), 0.0f);
    float ih = fmaxf(__fsub_rn(y2, y1), 0.0f);
    float inter = __fmul_rn(iw, ih);
    float uni = __fsub_rn(__fadd_rn(aA, bA), inter);
    if (!(uni > 0.0f)) return false;
    return __fdiv_rn(inter, uni) > IOU_TH;
}

__device__ __forceinline__ float4 load_box(const float* __restrict__ img,
                                           int boxoff, uint64_t key) {
    if ((key >> 32) == 0) return make_float4(0.f, 0.f, 0.f, 0.f);
    uint32_t i = 0xFFFFFFFFu - (uint32_t)key;
    const float* bp = img + (size_t)i * LASTD + boxoff;
    return make_float4(bp[0], bp[1], bp[2], bp[3]);
}

__device__ __forceinline__ float box_area(float4 b) {
    return __fmul_rn(__fsub_rn(b.z, b.x), __fsub_rn(b.w, b.y));
}

// Intra-batch pairwise suppression mask (bit t of lane L: candidate t<L would
// suppress L if accepted). Boxes exchanged via shfl; invalid partners have
// zero area -> iou false.
__device__ __forceinline__ void store_imask(SM* sm, int pp, float4 box, float a,
                                            bool valid, int wav, int lane) {
    uint64_t im = 0;
    #pragma unroll
    for (int tt = 0; tt < 4; ++tt) {
        int t = wav + tt * NW;
        float tx = __shfl(box.x, t), ty = __shfl(box.y, t);
        float tz = __shfl(box.z, t), tw = __shfl(box.w, t);
        float ta = __shfl(a, t);
        if (valid && t < lane &&
            iou_gt_pre(box.x, box.y, box.z, box.w, a, tx, ty, tz, tw, ta))
            im |= 1ull << t;
    }
    sm->imask[pp][wav][lane] = im;
}

// One block per (image, class): 2048-bin counting sort of all conf>0.5
// candidates into exact (score desc, idx asc) order, then a pipelined batched
// greedy scan (resolve of batch b on wave0 overlapped with ext-check of batch
// b+1 on waves 1-15), exactly replicating the reference's argmax+suppress
// scan. The last-finishing block of each image runs the top-200 merge inline.
__global__ __launch_bounds__(THREADS) void nms_topk(const float* __restrict__ yp,
                                                    float* __restrict__ rows,
                                                    int* __restrict__ ctr,
                                                    float* __restrict__ out) {
    __shared__ SM sm;
    const int task = blockIdx.x;
    const int b = task / NCM1;
    const int cm1 = task % NCM1;
    const int tid = threadIdx.x;
    const int lane = tid & 63;
    const int wav = tid >> 6;
    const float* img = yp + (size_t)b * NBOX * LASTD;
    const int boxoff = NCL + 4 * cm1;

    // ---- phase 1: conf column loads (all 9 in flight) ----
    float confs[NIT];
    #pragma unroll
    for (int it = 0; it < NIT; ++it) {
        int idx = it * THREADS + tid;
        confs[it] = (idx < NBOX) ? img[(size_t)idx * LASTD + (1 + cm1)] : 0.0f;
    }
    sm.hist[tid] = 0; sm.hist[tid + THREADS] = 0;
    if (tid == 0) { sm.supA[0] = 0ull; sm.supA[1] = 0ull; }
    __syncthreads();

    // ---- phase 2: 2048-bin histogram (top 11 mantissa bits, conf in (0.5,1)) --
    #pragma unroll
    for (int it = 0; it < NIT; ++it) {
        int idx = it * THREADS + tid;
        if (idx < NBOX && confs[it] > CONF_TH) {
            int bin = (int)((__float_as_uint(confs[it]) - 0x3F000000u) >> 12);
            atomicAdd(&sm.hist[bin], 1);
        }
    }
    __syncthreads();

    // ---- phase 3: descending bin bases via suffix-sum over bin pairs ----
    int h0 = sm.hist[2 * tid], h1 = sm.hist[2 * tid + 1];
    int x = h0 + h1;
    int s = x;
    #pragma unroll
    for (int d = 1; d <= 32; d <<= 1) {
        int y = __shfl_down(s, d);
        if (lane + d < 64) s += y;
    }
    if (lane == 0) sm.wavetot[wav] = s;
    __syncthreads();
    int cross = 0;
    #pragma unroll
    for (int w = 0; w < NW; ++w)
        if (w > wav) cross += sm.wavetot[w];
    int Safter = cross + s - x;               // keys in pairs strictly after
    sm.binstart[2 * tid + 1] = Safter;        // higher bin of the pair first
    sm.binstart[2 * tid] = Safter + h1;
    if (tid == 0) sm.Mshare = cross + s;
    sm.hist[2 * tid] = 0; sm.hist[2 * tid + 1] = 0;  // reuse as scatter ctr
    __syncthreads();

    // ---- phase 4: scatter to bin regions ----
    #pragma unroll
    for (int it = 0; it < NIT; ++it) {
        int idx = it * THREADS + tid;
        if (idx < NBOX && confs[it] > CONF_TH) {
            uint32_t bits = __float_as_uint(confs[it]);
            int bin = (int)((bits - 0x3F000000u) >> 12);
            int slot = sm.binstart[bin] + atomicAdd(&sm.hist[bin], 1);
            sm.keys[slot] = ((uint64_t)bits << 32) |
                            (uint32_t)(0xFFFFFFFFu - (uint32_t)idx);
        }
    }
    __syncthreads();
    const int M = sm.Mshare;
    for (int m = M + tid; m < KPAD; m += THREADS) sm.keys[m] = 0;
    // ---- phase 5: per-bin insertion sort (2 bins/thread, ~2 keys/bin) ----
    for (int f = tid; f < NBIN; f += THREADS) {
        int s0 = sm.binstart[f], h = sm.hist[f];
        for (int i2 = 1; i2 < h; ++i2) {
            uint64_t key = sm.keys[s0 + i2];
            int j = i2 - 1;
            while (j >= 0 && sm.keys[s0 + j] < key) {
                sm.keys[s0 + j + 1] = sm.keys[s0 + j];
                --j;
            }
            sm.keys[s0 + j + 1] = key;
        }
    }

    // ---- phase 6: pipelined greedy scan ----
    // Invariant entering iter i (parity p=i&1): supA[p] holds cur's ext-status
    // vs accepted[0..prevN) (from B of iter i-1); A adds [prevN..nsel); imask[p]
    // holds cur's intra-batch mask. Resolve(cur) on wave0 overlaps with full
    // ext-check of nxt vs [0..nselPre) on waves 1-15.
    uint64_t keyC = sm.keys[lane];            // keys stable: written pre-barrier
    uint64_t keyN0;
    __syncthreads();                          // publish keys (phase 5) + supA
    keyC = sm.keys[lane];
    keyN0 = sm.keys[64 + lane];
    float4 boxC = load_box(img, boxoff, keyC);
    float aC = box_area(boxC);
    uint64_t keyN = keyN0;
    float4 boxN = load_box(img, boxoff, keyN);
    float aN = box_area(boxN);
    store_imask(&sm, 0, boxC, aC, (keyC >> 32) != 0, wav, lane);
    __syncthreads();                          // publish imask[0]

    int nsel = 0, prevN = 0;
    bool done = false;
    for (int i = 0; i < NBATCH && !done; ++i) {
        const int p = i & 1;
        const bool vC = (keyC >> 32) != 0;
        // A: delta ext-check of cur vs newly accepted [prevN, nsel)
        bool sup = false;
        for (int j = prevN + wav; j < nsel; j += NW)
            sup |= iou_gt_pre(boxC.x, boxC.y, boxC.z, boxC.w, aC,
                              sm.selx[j], sm.sely[j], sm.selz[j], sm.selw[j],
                              sm.selA[j]);
        unsigned long long bal = __ballot(vC && sup);
        if (lane == 0 && bal) atomicOr(&sm.supA[p], bal);
        // imask for nxt batch -> other parity buffer
        store_imask(&sm, p ^ 1, boxN, aN, (keyN >> 32) != 0, wav, lane);
        // prefetch batch i+2
        int f0 = (i + 2) * 64;
        uint64_t key2 = (f0 < KPAD) ? sm.keys[f0 + lane] : 0;
        float4 box2 = load_box(img, boxoff, key2);
        float a2 = box_area(box2);
        __syncthreads();  // barrier 1: supA[p] complete, imask[p^1] published
        const int nselPre = nsel;
        if (wav == 0) {
            // resolve cur: sequential greedy over the 64-candidate batch
            unsigned long long V = __ballot(vC);
            unsigned long long E = sm.supA[p];
            if (lane == 0) sm.supA[p] = 0ull;
            uint64_t imf = 0;
            #pragma unroll
            for (int w = 0; w < NW; ++w) imf |= sm.imask[p][w][lane];
            uint64_t alive = ~(E | ~V);
            uint64_t accm = 0;
            int cnt = nsel;
            while (alive && cnt < MAXOUT) {
                int t = __ffsll((unsigned long long)alive) - 1;
                alive &= alive - 1;
                accm |= 1ull << t;
                cnt++;
                unsigned long long supt = __ballot((imf >> t) & 1ull);
                alive &= ~supt;
            }
            if ((accm >> lane) & 1ull) {
                int pos = nsel + __popcll(accm & ((1ull << lane) - 1ull));
                sm.selx[pos] = boxC.x; sm.sely[pos] = boxC.y;
                sm.selz[pos] = boxC.z; sm.selw[pos] = boxC.w;
                sm.selA[pos] = aC;     sm.selkey[pos] = keyC;
            }
            if (lane == 0) {
                sm.nselshare = cnt;
                sm.prevNshare = nselPre;
                sm.doneflag = (cnt >= MAXOUT) || (V != ~0ull);
            }
        } else {
            // full ext-check of nxt vs accepted snapshot [0..nselPre)
            const bool vN = (keyN >> 32) != 0;
            bool supN = false;
            for (int j = wav - 1; j < nselPre; j += NW - 1)
                supN |= iou_gt_pre(boxN.x, boxN.y, boxN.z, boxN.w, aN,
                                   sm.selx[j], sm.sely[j], sm.selz[j],
                                   sm.selw[j], sm.selA[j]);
            unsigned long long balN = __ballot(vN && supN);
            if (lane == 0 && balN) atomicOr(&sm.supA[p ^ 1], balN);
        }
        __syncthreads();  // barrier 2: accepts + counters published
        nsel = sm.nselshare;
        prevN = sm.prevNshare;
        done = sm.doneflag != 0;
        keyC = keyN; boxC = boxN; aC = aN;
        keyN = key2; boxN = box2; aN = a2;
    }

    // ---- phase 7: emit 400 rows [class, conf, x1,y1,x2,y2, extra] ----
    float* out0 = rows + (size_t)task * MAXOUT * 7;
    for (int r = tid; r < MAXOUT; r += THREADS) {
        float* o = out0 + (size_t)r * 7;
        if (r < nsel) {
            uint64_t key = sm.selkey[r];
            uint32_t i = 0xFFFFFFFFu - (uint32_t)key;
            o[0] = (float)(cm1 + 1);
            o[1] = __uint_as_float((uint32_t)(key >> 32));
            o[2] = sm.selx[r];
            o[3] = sm.sely[r];
            o[4] = sm.selz[r];
            o[5] = sm.selw[r];
            o[6] = img[(size_t)i * LASTD + (LASTD - 1)];
        } else {
            #pragma unroll
            for (int q = 0; q < 7; ++q) o[q] = 0.0f;
        }
    }

    // ---- phase 8: fused top-200 — last block of each image merges ----
    __threadfence();   // release: rows writes device-visible
    __syncthreads();
    if (tid == 0) sm.lastflag = (atomicAdd(&ctr[b], 1) == NCM1 - 1);
    __syncthreads();
    if (!sm.lastflag) return;
    __threadfence();   // acquire: other blocks' rows visible

    // Per-class lists are score-descending; top-200 never needs within-class
    // rank >= 256: 32 lists x 256 keys, 5 rounds of bitonic top-256 merges.
    uint64_t* K = sm.keys;  // reuse (70 KB >= 64 KB)
    const float* rb = rows + (size_t)b * (NCM1 * MAXOUT) * 7;
    for (int xx = tid; xx < 8192; xx += THREADS) {
        int list = xx >> 8, r = xx & 255;
        uint64_t k = 0;
        if (list < NCM1) {
            int flat = list * MAXOUT + r;
            float conf = rb[(size_t)flat * 7 + 1];
            k = ((uint64_t)__float_as_uint(conf) << 32) |
                (uint32_t)(0xFFFFFFFFu - (uint32_t)flat);
        }
        K[xx] = k;
    }
    __syncthreads();
    for (int round = 0; round < 5; ++round) {
        int npairs = 16 >> round;
        int sep = 256 << round;
        for (int w = tid; w < npairs * 256; w += THREADS) {
            int pp = w >> 8, t = w & 255;
            int A = pp * 2 * sep;
            uint64_t a = K[A + t];
            uint64_t c = K[A + sep + 255 - t];
            K[A + t] = a > c ? a : c;
        }
        __syncthreads();
        for (int j = 128; j >= 1; j >>= 1) {
            for (int w = tid; w < npairs * 128; w += THREADS) {
                int pp = w >> 7, q = w & 127;
                int t = ((q & ~(j - 1)) << 1) | (q & (j - 1));
                int A = pp * 2 * sep;
                uint64_t x0 = K[A + t];
                uint64_t x1 = K[A + t + j];
                if (x0 < x1) { K[A + t] = x1; K[A + t + j] = x0; }
            }
            __syncthreads();
        }
    }
    if (tid < TOPK) {
        uint64_t key = K[tid];
        uint32_t flat = 0xFFFFFFFFu - (uint32_t)key;
        const float* src = rb + (size_t)flat * 7;
        float* o = out + ((size_t)b * TOPK + tid) * 7;
        #pragma unroll
        for (int q = 0; q < 7; ++q) o[q] = src[q];
    }
}

extern "C" void kernel_launch(void* const* d_in, const int* in_sizes, int n_in,
                              void* d_out, int out_size, void* d_ws, size_t ws_size,
                              hipStream_t stream) {
    const float* yp = (const float*)d_in[0];
    float* rows = (float*)d_ws;  // NTASK*400*7 floats = 1.792 MB
    int* ctr = (int*)((char*)d_ws + (size_t)NTASK * MAXOUT * 7 * sizeof(float));
    hipMemsetAsync(ctr, 0, NB * sizeof(int), stream);
    hipLaunchKernelGGL(nms_topk, dim3(NTASK), dim3(THREADS), 0, stream,
                       yp, rows, ctr, (float*)d_out);
}

// Round 6
// 111.004 us; speedup vs baseline: 1.5608x; 1.5608x over previous
//
#include <hip/hip_runtime.h>
#include <cstdint>

#define NB 8
#define NBOX 8732
#define NCL 21
#define NCM1 20
#define LASTD 102
#define CONF_TH 0.5f
#define IOU_TH 0.45f
#define TOPK 200
#define MAXOUT 400
#define NTASK (NB * NCM1)
#define THREADS 1024
#define NW 16
#define NIT 9          // ceil(8732/1024)
#define NBIN 2048
#define KPAD 8768      // 64*137 >= NBOX: counting-sorted keys always fit

struct SM {
    float4 selbox[MAXOUT];       // 6.4 KB (16B aligned first)
    uint64_t keys[KPAD];         // 70.1 KB
    uint64_t selkey[MAXOUT];     // 3.2 KB
    uint64_t imask[NW][64];      // 8 KB
    int hist[NBIN];              // 8 KB (histogram, then scatter counter)
    int binstart[NBIN];          // 8 KB
    int wavetot[NW];
    unsigned long long supAll;
    int Mshare, nselshare, doneflag;
};

// Branchless IoU(>0.45) with explicit RN ops matching the host fp32 reference
// bit-for-bit: inter via max/min, areas per-box, union=(aa+ab)-inter, fdiv,
// strict >. uni<=0 (incl. zero-area invalid boxes) -> 0 (nan>TH is false).
__device__ __forceinline__ int iou_gt(float4 a, float4 b) {
    float x1 = fmaxf(a.x, b.x), y1 = fmaxf(a.y, b.y);
    float x2 = fminf(a.z, b.z), y2 = fminf(a.w, b.w);
    float iw = fmaxf(__fsub_rn(x2, x1), 0.0f);
    float ih = fmaxf(__fsub_rn(y2, y1), 0.0f);
    float inter = __fmul_rn(iw, ih);
    float aa = __fmul_rn(__fsub_rn(a.z, a.x), __fsub_rn(a.w, a.y));
    float ab = __fmul_rn(__fsub_rn(b.z, b.x), __fsub_rn(b.w, b.y));
    float uni = __fsub_rn(__fadd_rn(aa, ab), inter);
    return (uni > 0.0f) & (__fdiv_rn(inter, uni) > IOU_TH);
}

__device__ __forceinline__ float4 load_box(const float* __restrict__ img,
                                           int boxoff, uint64_t key) {
    if ((key >> 32) == 0) return make_float4(0.f, 0.f, 0.f, 0.f);
    uint32_t i = 0xFFFFFFFFu - (uint32_t)key;
    const float* bp = img + (size_t)i * LASTD + boxoff;
    return make_float4(bp[0], bp[1], bp[2], bp[3]);
}

// One block per (image, class): 2048-bin counting sort of all conf>0.5
// candidates into exact (score desc, idx asc) order, then batched greedy NMS
// scan exactly replicating the reference's 400-step argmax+suppress loop.
__global__ __launch_bounds__(THREADS) void nms_per_class(const float* __restrict__ yp,
                                                         float* __restrict__ rows) {
    __shared__ SM sm;
    const int task = blockIdx.x;
    const int b = task / NCM1;
    const int cm1 = task % NCM1;
    const int tid = threadIdx.x;
    const int lane = tid & 63;
    const int wav = tid >> 6;
    const float* img = yp + (size_t)b * NBOX * LASTD;
    const int boxoff = NCL + 4 * cm1;

    // ---- phase 1: conf column loads (all 9 in flight) ----
    float confs[NIT];
    #pragma unroll
    for (int it = 0; it < NIT; ++it) {
        int idx = it * THREADS + tid;
        confs[it] = (idx < NBOX) ? img[(size_t)idx * LASTD + (1 + cm1)] : 0.0f;
    }
    sm.hist[tid] = 0; sm.hist[tid + THREADS] = 0;
    if (tid == 0) sm.supAll = 0ull;
    __syncthreads();

    // ---- phase 2: 2048-bin histogram (top 11 mantissa bits, conf in (0.5,1)) --
    #pragma unroll
    for (int it = 0; it < NIT; ++it) {
        int idx = it * THREADS + tid;
        if (idx < NBOX && confs[it] > CONF_TH) {
            int bin = (int)((__float_as_uint(confs[it]) - 0x3F000000u) >> 12);
            atomicAdd(&sm.hist[bin], 1);
        }
    }
    __syncthreads();

    // ---- phase 3: descending bin bases via suffix-sum over bin pairs ----
    int h0 = sm.hist[2 * tid], h1 = sm.hist[2 * tid + 1];
    int x = h0 + h1;
    int s = x;
    #pragma unroll
    for (int d = 1; d <= 32; d <<= 1) {
        int y = __shfl_down(s, d);
        if (lane + d < 64) s += y;
    }
    if (lane == 0) sm.wavetot[wav] = s;
    __syncthreads();
    int cross = 0;
    #pragma unroll
    for (int w = 0; w < NW; ++w)
        if (w > wav) cross += sm.wavetot[w];
    int Safter = cross + s - x;               // keys in bins strictly above
    sm.binstart[2 * tid + 1] = Safter;        // higher bin (higher score) first
    sm.binstart[2 * tid] = Safter + h1;
    if (tid == 0) sm.Mshare = cross + s;
    sm.hist[2 * tid] = 0; sm.hist[2 * tid + 1] = 0;  // reuse as scatter ctr
    __syncthreads();

    // ---- phase 4: scatter keys to bin regions ----
    #pragma unroll
    for (int it = 0; it < NIT; ++it) {
        int idx = it * THREADS + tid;
        if (idx < NBOX && confs[it] > CONF_TH) {
            uint32_t bits = __float_as_uint(confs[it]);
            int bin = (int)((bits - 0x3F000000u) >> 12);
            int slot = sm.binstart[bin] + atomicAdd(&sm.hist[bin], 1);
            sm.keys[slot] = ((uint64_t)bits << 32) |
                            (uint32_t)(0xFFFFFFFFu - (uint32_t)idx);
        }
    }
    __syncthreads();
    const int M = sm.Mshare;
    for (int m = M + tid; m < KPAD; m += THREADS) sm.keys[m] = 0;
    // ---- phase 5: per-bin insertion sort (2 bins/thread, ~2 keys/bin) ----
    for (int f = tid; f < NBIN; f += THREADS) {
        int s0 = sm.binstart[f], h = sm.hist[f];
        for (int i2 = 1; i2 < h; ++i2) {
            uint64_t key = sm.keys[s0 + i2];
            int j = i2 - 1;
            while (j >= 0 && sm.keys[s0 + j] < key) {
                sm.keys[s0 + j + 1] = sm.keys[s0 + j];
                --j;
            }
            sm.keys[s0 + j + 1] = key;
        }
    }
    __syncthreads();

    // ---- phase 6: batched greedy scan, 64 cand/batch, next-batch prefetch ----
    int nsel = 0;
    bool done = false;
    uint64_t key_n = sm.keys[lane];
    float4 box_n = load_box(img, boxoff, key_n);
    for (int cb0 = 0; cb0 < KPAD && !done; cb0 += 64) {
        uint64_t mykey = key_n;
        float4 mybox = box_n;
        // prefetch next batch (keys stable during scan; hides box gather)
        int nb0 = cb0 + 64;
        key_n = (nb0 < KPAD) ? sm.keys[nb0 + lane] : 0;
        box_n = load_box(img, boxoff, key_n);
        bool valid = (mykey >> 32) != 0;
        // ext-suppression vs accepted list: waves split the j range; 4x
        // unrolled with grouped loads so 4 LDS b128 reads are in flight.
        int sup0 = 0, sup1 = 0, sup2 = 0, sup3 = 0;
        int j = wav;
        for (; j + 3 * NW < nsel; j += 4 * NW) {
            float4 s0 = sm.selbox[j];
            float4 s1 = sm.selbox[j + NW];
            float4 s2 = sm.selbox[j + 2 * NW];
            float4 s3 = sm.selbox[j + 3 * NW];
            sup0 |= iou_gt(mybox, s0);
            sup1 |= iou_gt(mybox, s1);
            sup2 |= iou_gt(mybox, s2);
            sup3 |= iou_gt(mybox, s3);
        }
        for (; j < nsel; j += NW) sup0 |= iou_gt(mybox, sm.selbox[j]);
        bool sup = (sup0 | sup1 | sup2 | sup3) != 0;
        unsigned long long bal = __ballot(valid && sup);
        if (lane == 0 && bal) atomicOr(&sm.supAll, bal);
        // intra-batch pairwise IoU; candidate boxes fetched via shfl
        uint64_t im = 0;
        #pragma unroll
        for (int tt = 0; tt < 4; ++tt) {
            int t = wav + tt * NW;
            float4 tb;
            tb.x = __shfl(mybox.x, t); tb.y = __shfl(mybox.y, t);
            tb.z = __shfl(mybox.z, t); tb.w = __shfl(mybox.w, t);
            if (valid && t < lane && iou_gt(mybox, tb))
                im |= 1ull << t;
        }
        sm.imask[wav][lane] = im;
        unsigned long long V = __ballot(valid);
        __syncthreads();  // barrier 1: supAll + imask published
        if (wav == 0) {
            unsigned long long E = sm.supAll;
            if (lane == 0) sm.supAll = 0ull;
            uint64_t imf = 0;
            #pragma unroll
            for (int w = 0; w < NW; ++w) imf |= sm.imask[w][lane];
            uint64_t alive = ~(E | ~V);
            uint64_t accm = 0;
            int cnt = nsel;
            while (alive && cnt < MAXOUT) {
                int t = __ffsll((unsigned long long)alive) - 1;
                alive &= alive - 1;
                accm |= 1ull << t;
                cnt++;
                unsigned long long supt = __ballot((imf >> t) & 1ull);
                alive &= ~supt;
            }
            if ((accm >> lane) & 1ull) {
                int pos = nsel + __popcll(accm & ((1ull << lane) - 1ull));
                sm.selbox[pos] = mybox;
                sm.selkey[pos] = mykey;
            }
            if (lane == 0) {
                sm.nselshare = cnt;
                sm.doneflag = (cnt >= MAXOUT) || (V != ~0ull);
            }
        }
        __syncthreads();  // barrier 2: accepted boxes + nsel published
        nsel = sm.nselshare;
        done = sm.doneflag != 0;
    }

    // ---- phase 7: emit 400 rows [class, conf, x1,y1,x2,y2, extra] ----
    float* out0 = rows + (size_t)task * MAXOUT * 7;
    for (int r = tid; r < MAXOUT; r += THREADS) {
        float* o = out0 + (size_t)r * 7;
        if (r < nsel) {
            uint64_t key = sm.selkey[r];
            uint32_t i = 0xFFFFFFFFu - (uint32_t)key;
            float4 bx = sm.selbox[r];
            o[0] = (float)(cm1 + 1);
            o[1] = __uint_as_float((uint32_t)(key >> 32));
            o[2] = bx.x;
            o[3] = bx.y;
            o[4] = bx.z;
            o[5] = bx.w;
            o[6] = img[(size_t)i * LASTD + (LASTD - 1)];
        } else {
            #pragma unroll
            for (int q = 0; q < 7; ++q) o[q] = 0.0f;
        }
    }
}

// One block per image: top-200 by (conf desc, flat idx asc) over 20*400 rows.
// Per-class lists are already sorted desc; top-200 never needs within-class
// rank >= 256, so: 32 lists x 256 keys, 5 rounds of pairwise bitonic top-256
// merges (max-combine + 8 merge stages), then gather the first 200 rows.
__global__ __launch_bounds__(THREADS) void topk_per_image(const float* __restrict__ rows,
                                                          float* __restrict__ out) {
    __shared__ uint64_t K[8192];
    const int b = blockIdx.x;
    const int tid = threadIdx.x;
    const float* rb = rows + (size_t)b * (NCM1 * MAXOUT) * 7;

    for (int xx = tid; xx < 8192; xx += THREADS) {
        int list = xx >> 8, r = xx & 255;
        uint64_t k = 0;
        if (list < NCM1) {
            int flat = list * MAXOUT + r;
            float conf = rb[(size_t)flat * 7 + 1];
            k = ((uint64_t)__float_as_uint(conf) << 32) |
                (uint32_t)(0xFFFFFFFFu - (uint32_t)flat);
        }
        K[xx] = k;
    }
    __syncthreads();

    for (int round = 0; round < 5; ++round) {
        int npairs = 16 >> round;
        int sep = 256 << round;
        for (int w = tid; w < npairs * 256; w += THREADS) {
            int p = w >> 8, t = w & 255;
            int A = p * 2 * sep;
            uint64_t a = K[A + t];
            uint64_t c = K[A + sep + 255 - t];
            K[A + t] = a > c ? a : c;
        }
        __syncthreads();
        for (int j = 128; j >= 1; j >>= 1) {
            for (int w = tid; w < npairs * 128; w += THREADS) {
                int p = w >> 7, q = w & 127;
                int t = ((q & ~(j - 1)) << 1) | (q & (j - 1));
                int A = p * 2 * sep;
                uint64_t x0 = K[A + t];
                uint64_t x1 = K[A + t + j];
                if (x0 < x1) { K[A + t] = x1; K[A + t + j] = x0; }
            }
            __syncthreads();
        }
    }

    if (tid < TOPK) {
        uint64_t key = K[tid];
        uint32_t flat = 0xFFFFFFFFu - (uint32_t)key;
        const float* src = rb + (size_t)flat * 7;
        float* o = out + ((size_t)b * TOPK + tid) * 7;
        #pragma unroll
        for (int q = 0; q < 7; ++q) o[q] = src[q];
    }
}

extern "C" void kernel_launch(void* const* d_in, const int* in_sizes, int n_in,
                              void* d_out, int out_size, void* d_ws, size_t ws_size,
                              hipStream_t stream) {
    const float* yp = (const float*)d_in[0];
    float* rows = (float*)d_ws;  // NTASK*400*7 floats = 1.792 MB scratch
    float* out = (float*)d_out;

    hipLaunchKernelGGL(nms_per_class, dim3(NTASK), dim3(THREADS), 0, stream, yp, rows);
    hipLaunchKernelGGL(topk_per_image, dim3(NB), dim3(THREADS), 0, stream, rows, out);
}

// Round 7
// 100.660 us; speedup vs baseline: 1.7211x; 1.1028x over previous
//
#include <hip/hip_runtime.h>
#include <cstdint>

#define NB 8
#define NBOX 8732
#define NCL 21
#define NCM1 20
#define LASTD 102
#define CONF_TH 0.5f
#define IOU_TH 0.45f
#define TOPK 200
#define MAXOUT 400
#define NTASK (NB * NCM1)
#define THREADS 1024
#define NW 16
#define NIT 9          // ceil(8732/1024)
#define NBIN 2048
#define KPAD 8768      // 64*137 >= NBOX: counting-sorted keys always fit
#define NBATCH (KPAD / 64)

// Exact equivalence (proven): uni>0 && RN_f32(inter/uni) > 0.45f
//   <=>  uni>0 && (double)inter > MIDD*(double)uni
// MIDD = double(0.45f) + 2^-26 (midpoint above 0.45f). 0.45f mantissa is even,
// so a quotient exactly at the midpoint rounds to 0.45f (not >). MIDD has 25
// mantissa bits; uni has 24; the f64 product (<=49 bits) is exact.
#define MIDD ((double)IOU_TH + 0x1p-26)

struct SM {
    float4 selbox[MAXOUT];        // 6.4 KB
    float selA[MAXOUT];           // 1.6 KB (accepted areas)
    uint64_t selkey[MAXOUT];      // 3.2 KB
    uint64_t keys[KPAD];          // 70.1 KB
    uint64_t vmask[2][64];        // 1 KB, double-buffered victim masks
    unsigned long long supW[2][NW];  // per-wave ext-suppression ballots
    int hist[NBIN];               // 8 KB
    int binstart[NBIN];           // 8 KB
    int wavetot[NW];
    int Mshare, nselshare, prevNshare, doneflag;
};  // ~99 KB

// IoU(>0.45) with precomputed areas; explicit RN ops + exact double compare
// match the host fp32 reference bit-for-bit.
__device__ __forceinline__ int iou_sup(float4 a, float aA, float4 b, float bA) {
    float x1 = fmaxf(a.x, b.x), y1 = fmaxf(a.y, b.y);
    float x2 = fminf(a.z, b.z), y2 = fminf(a.w, b.w);
    float iw = fmaxf(__fsub_rn(x2, x1), 0.0f);
    float ih = fmaxf(__fsub_rn(y2, y1), 0.0f);
    float inter = __fmul_rn(iw, ih);
    float uni = __fsub_rn(__fadd_rn(aA, bA), inter);
    return (uni > 0.0f) & ((double)inter > MIDD * (double)uni);
}

__device__ __forceinline__ float4 load_box(const float* __restrict__ img,
                                           int boxoff, uint64_t key) {
    if ((key >> 32) == 0) return make_float4(0.f, 0.f, 0.f, 0.f);
    uint32_t i = 0xFFFFFFFFu - (uint32_t)key;
    const float* bp = img + (size_t)i * LASTD + boxoff;
    return make_float4(bp[0], bp[1], bp[2], bp[3]);
}

__device__ __forceinline__ float box_area(float4 b) {
    return __fmul_rn(__fsub_rn(b.z, b.x), __fsub_rn(b.w, b.y));
}

// Victim masks for one 64-candidate batch: vmask[t] = ballot of lanes L with
// t<L and IoU(t,L)>0.45 (valid L). Wave w owns t in {w, w+16, w+32, w+48}.
__device__ __forceinline__ void compute_vmask(SM* sm, int pp, float4 box,
                                              float a, bool valid, int wav,
                                              int lane) {
    #pragma unroll
    for (int tt = 0; tt < 4; ++tt) {
        int t = wav + tt * NW;
        float4 tb;
        tb.x = __shfl(box.x, t); tb.y = __shfl(box.y, t);
        tb.z = __shfl(box.z, t); tb.w = __shfl(box.w, t);
        float ta = __shfl(a, t);
        unsigned long long vm =
            __ballot(valid && t < lane && iou_sup(box, a, tb, ta));
        if (lane == t) sm->vmask[pp][t] = vm;
    }
}

// One block per (image, class): 2048-bin counting sort of all conf>0.5
// candidates into exact (score desc, idx asc) order, then a split-wave
// pipelined greedy scan (wave0 resolves batch i while waves 1-15 ext-check
// batch i+1), exactly replicating the reference's argmax+suppress loop.
__global__ __launch_bounds__(THREADS) void nms_per_class(const float* __restrict__ yp,
                                                         float* __restrict__ rows) {
    __shared__ SM sm;
    const int task = blockIdx.x;
    const int b = task / NCM1;
    const int cm1 = task % NCM1;
    const int tid = threadIdx.x;
    const int lane = tid & 63;
    const int wav = tid >> 6;
    const float* img = yp + (size_t)b * NBOX * LASTD;
    const int boxoff = NCL + 4 * cm1;

    // ---- phase 1: conf column loads (all 9 in flight) ----
    float confs[NIT];
    #pragma unroll
    for (int it = 0; it < NIT; ++it) {
        int idx = it * THREADS + tid;
        confs[it] = (idx < NBOX) ? img[(size_t)idx * LASTD + (1 + cm1)] : 0.0f;
    }
    sm.hist[tid] = 0; sm.hist[tid + THREADS] = 0;
    if (tid < 2 * NW) ((unsigned long long*)sm.supW)[tid] = 0ull;
    __syncthreads();

    // ---- phase 2: 2048-bin histogram (top 11 mantissa bits, conf in (0.5,1)) --
    #pragma unroll
    for (int it = 0; it < NIT; ++it) {
        int idx = it * THREADS + tid;
        if (idx < NBOX && confs[it] > CONF_TH) {
            int bin = (int)((__float_as_uint(confs[it]) - 0x3F000000u) >> 12);
            atomicAdd(&sm.hist[bin], 1);
        }
    }
    __syncthreads();

    // ---- phase 3: descending bin bases via suffix-sum over bin pairs ----
    int h0 = sm.hist[2 * tid], h1 = sm.hist[2 * tid + 1];
    int x = h0 + h1;
    int s = x;
    #pragma unroll
    for (int d = 1; d <= 32; d <<= 1) {
        int y = __shfl_down(s, d);
        if (lane + d < 64) s += y;
    }
    if (lane == 0) sm.wavetot[wav] = s;
    __syncthreads();
    int cross = 0;
    #pragma unroll
    for (int w = 0; w < NW; ++w)
        if (w > wav) cross += sm.wavetot[w];
    int Safter = cross + s - x;               // keys in bins strictly above
    sm.binstart[2 * tid + 1] = Safter;        // higher bin (higher score) first
    sm.binstart[2 * tid] = Safter + h1;
    if (tid == 0) sm.Mshare = cross + s;
    sm.hist[2 * tid] = 0; sm.hist[2 * tid + 1] = 0;  // reuse as scatter ctr
    __syncthreads();

    // ---- phase 4: scatter keys to bin regions ----
    #pragma unroll
    for (int it = 0; it < NIT; ++it) {
        int idx = it * THREADS + tid;
        if (idx < NBOX && confs[it] > CONF_TH) {
            uint32_t bits = __float_as_uint(confs[it]);
            int bin = (int)((bits - 0x3F000000u) >> 12);
            int slot = sm.binstart[bin] + atomicAdd(&sm.hist[bin], 1);
            sm.keys[slot] = ((uint64_t)bits << 32) |
                            (uint32_t)(0xFFFFFFFFu - (uint32_t)idx);
        }
    }
    __syncthreads();
    const int M = sm.Mshare;
    for (int m = M + tid; m < KPAD; m += THREADS) sm.keys[m] = 0;
    // ---- phase 5: per-bin insertion sort (2 bins/thread, ~2 keys/bin) ----
    for (int f = tid; f < NBIN; f += THREADS) {
        int s0 = sm.binstart[f], h = sm.hist[f];
        for (int i2 = 1; i2 < h; ++i2) {
            uint64_t key = sm.keys[s0 + i2];
            int j = i2 - 1;
            while (j >= 0 && sm.keys[s0 + j] < key) {
                sm.keys[s0 + j + 1] = sm.keys[s0 + j];
                --j;
            }
            sm.keys[s0 + j + 1] = key;
        }
    }
    __syncthreads();

    // ---- phase 6: split-wave pipelined greedy scan ----
    // Parity p = i&1. Entering iter i: supW[p] holds cur's ext-ballots vs
    // accepted[0..prevN) (from full-check at iter i-1); vmask[p] holds cur's
    // intra-batch victim masks. Delta-check covers [prevN..nsel). Resolve(cur)
    // on wave0 overlaps full ext-check of nxt vs [0..nselPre) on waves 1-15.
    uint64_t keyC = sm.keys[lane];
    uint64_t keyN = sm.keys[64 + lane];
    float4 boxC = load_box(img, boxoff, keyC);
    float4 boxN = load_box(img, boxoff, keyN);
    float aC = box_area(boxC), aN = box_area(boxN);
    compute_vmask(&sm, 0, boxC, aC, (keyC >> 32) != 0, wav, lane);

    int nsel = 0, prevN = 0;
    bool done = false;
    for (int i = 0; i < NBATCH && !done; ++i) {
        const int p = i & 1;
        const bool vC = (keyC >> 32) != 0;
        const bool vN = (keyN >> 32) != 0;
        // A: delta ext-check of cur vs newly accepted [prevN, nsel)
        {
            int sup = 0;
            for (int j = prevN + wav; j < nsel; j += NW)
                sup |= iou_sup(boxC, aC, sm.selbox[j], sm.selA[j]);
            unsigned long long bal = __ballot(vC && sup);
            if (lane == 0 && bal) atomicOr(&sm.supW[p][wav], bal);
        }
        // B: victim masks for nxt -> other parity buffer
        compute_vmask(&sm, p ^ 1, boxN, aN, vN, wav, lane);
        // C: prefetch batch i+2
        int f0 = (i + 2) * 64;
        uint64_t key2 = (f0 < KPAD) ? sm.keys[f0 + lane] : 0;
        float4 box2 = load_box(img, boxoff, key2);
        float a2 = box_area(box2);
        __syncthreads();  // [1] supW[p], vmask[p^1] final; snapshot nsel
        const int nselPre = nsel;
        if (wav == 0) {
            // resolve cur: sequential greedy over 64 candidates
            unsigned long long V = __ballot(vC);
            unsigned long long E = (lane < NW) ? sm.supW[p][lane] : 0ull;
            #pragma unroll
            for (int d = 1; d < NW; d <<= 1) E |= __shfl_xor(E, d);
            E = __shfl(E, 0);
            if (lane < NW) sm.supW[p][lane] = 0ull;   // recycle for batch i+2
            uint64_t vm = sm.vmask[p][lane];
            uint64_t alive = ~(E | ~V);
            uint64_t accm = 0;
            int cnt = nsel;
            while (alive && cnt < MAXOUT) {
                int t = __ffsll((unsigned long long)alive) - 1;
                accm |= 1ull << t;
                cnt++;
                uint64_t vt = (uint64_t)__shfl((unsigned long long)vm, t);
                alive &= ~vt;
                alive &= ~(1ull << t);
            }
            if ((accm >> lane) & 1ull) {
                int pos = nsel + __popcll(accm & ((1ull << lane) - 1ull));
                sm.selbox[pos] = boxC;
                sm.selA[pos] = aC;
                sm.selkey[pos] = keyC;
            }
            if (lane == 0) {
                sm.nselshare = cnt;
                sm.prevNshare = nselPre;
                sm.doneflag = (cnt >= MAXOUT) || (V != ~0ull);
            }
        } else {
            // full ext-check of nxt vs accepted snapshot [0..nselPre)
            int supN = 0;
            for (int j = wav - 1; j < nselPre; j += NW - 1)
                supN |= iou_sup(boxN, aN, sm.selbox[j], sm.selA[j]);
            unsigned long long balN = __ballot(vN && supN);
            if (lane == 0 && balN) atomicOr(&sm.supW[p ^ 1][wav], balN);
        }
        __syncthreads();  // [2] accepts + counters published
        nsel = sm.nselshare;
        prevN = sm.prevNshare;
        done = sm.doneflag != 0;
        keyC = keyN; boxC = boxN; aC = aN;
        keyN = key2; boxN = box2; aN = a2;
    }

    // ---- phase 7: emit 400 rows [class, conf, x1,y1,x2,y2, extra] ----
    float* out0 = rows + (size_t)task * MAXOUT * 7;
    for (int r = tid; r < MAXOUT; r += THREADS) {
        float* o = out0 + (size_t)r * 7;
        if (r < nsel) {
            uint64_t key = sm.selkey[r];
            uint32_t i = 0xFFFFFFFFu - (uint32_t)key;
            float4 bx = sm.selbox[r];
            o[0] = (float)(cm1 + 1);
            o[1] = __uint_as_float((uint32_t)(key >> 32));
            o[2] = bx.x;
            o[3] = bx.y;
            o[4] = bx.z;
            o[5] = bx.w;
            o[6] = img[(size_t)i * LASTD + (LASTD - 1)];
        } else {
            #pragma unroll
            for (int q = 0; q < 7; ++q) o[q] = 0.0f;
        }
    }
}

// One block per image: top-200 by (conf desc, flat idx asc) over 20*400 rows.
// Per-class lists are already sorted desc; top-200 never needs within-class
// rank >= 256, so: 32 lists x 256 keys, 5 rounds of pairwise bitonic top-256
// merges (max-combine + 8 merge stages), then gather the first 200 rows.
__global__ __launch_bounds__(THREADS) void topk_per_image(const float* __restrict__ rows,
                                                          float* __restrict__ out) {
    __shared__ uint64_t K[8192];
    const int b = blockIdx.x;
    const int tid = threadIdx.x;
    const float* rb = rows + (size_t)b * (NCM1 * MAXOUT) * 7;

    for (int xx = tid; xx < 8192; xx += THREADS) {
        int list = xx >> 8, r = xx & 255;
        uint64_t k = 0;
        if (list < NCM1) {
            int flat = list * MAXOUT + r;
            float conf = rb[(size_t)flat * 7 + 1];
            k = ((uint64_t)__float_as_uint(conf) << 32) |
                (uint32_t)(0xFFFFFFFFu - (uint32_t)flat);
        }
        K[xx] = k;
    }
    __syncthreads();

    for (int round = 0; round < 5; ++round) {
        int npairs = 16 >> round;
        int sep = 256 << round;
        for (int w = tid; w < npairs * 256; w += THREADS) {
            int p = w >> 8, t = w & 255;
            int A = p * 2 * sep;
            uint64_t a = K[A + t];
            uint64_t c = K[A + sep + 255 - t];
            K[A + t] = a > c ? a : c;
        }
        __syncthreads();
        for (int j = 128; j >= 1; j >>= 1) {
            for (int w = tid; w < npairs * 128; w += THREADS) {
                int p = w >> 7, q = w & 127;
                int t = ((q & ~(j - 1)) << 1) | (q & (j - 1));
                int A = p * 2 * sep;
                uint64_t x0 = K[A + t];
                uint64_t x1 = K[A + t + j];
                if (x0 < x1) { K[A + t] = x1; K[A + t + j] = x0; }
            }
            __syncthreads();
        }
    }

    if (tid < TOPK) {
        uint64_t key = K[tid];
        uint32_t flat = 0xFFFFFFFFu - (uint32_t)key;
        const float* src = rb + (size_t)flat * 7;
        float* o = out + ((size_t)b * TOPK + tid) * 7;
        #pragma unroll
        for (int q = 0; q < 7; ++q) o[q] = src[q];
    }
}

extern "C" void kernel_launch(void* const* d_in, const int* in_sizes, int n_in,
                              void* d_out, int out_size, void* d_ws, size_t ws_size,
                              hipStream_t stream) {
    const float* yp = (const float*)d_in[0];
    float* rows = (float*)d_ws;  // NTASK*400*7 floats = 1.792 MB scratch
    float* out = (float*)d_out;

    hipLaunchKernelGGL(nms_per_class, dim3(NTASK), dim3(THREADS), 0, stream, yp, rows);
    hipLaunchKernelGGL(topk_per_image, dim3(NB), dim3(THREADS), 0, stream, rows, out);
}

// Round 8
// 70.870 us; speedup vs baseline: 2.4446x; 1.4204x over previous
//
#include <hip/hip_runtime.h>
#include <cstdint>

#define NB 8
#define NBOX 8732
#define NCL 21
#define NCM1 20
#define LASTD 102
#define CONF_TH 0.5f
#define IOU_TH 0.45f
#define TOPK 200
#define MAXOUT 400     // reference row pitch (flat tie-break encoding)
#define SELCAP 200     // provably sufficient accept cap (== TOPK)
#define EMITN 256      // topk reads within-class ranks [0,256) only
#define NTASK (NB * NCM1)
#define THREADS 1024
#define NW 16
#define NIT 9          // ceil(8732/1024)
#define NBIN 2048
#define KPAD 8768      // 64*137 >= NBOX: counting-sorted keys always fit
#define NBATCH (KPAD / 64)

// Exact equivalence (proven): uni>0 && RN_f32(inter/uni) > 0.45f
//   <=>  uni>0 && (double)inter > MIDD*(double)uni
// MIDD = double(0.45f) + 2^-26 (midpoint above 0.45f). 0.45f mantissa is even,
// so a quotient exactly at the midpoint rounds to 0.45f (not >). MIDD has 25
// mantissa bits; uni has 24; the f64 product (<=49 bits) is exact.
#define MIDD ((double)IOU_TH + 0x1p-26)

struct SM {
    float4 selbox[SELCAP];        // 3.2 KB
    float selA[SELCAP];           // 0.8 KB (accepted areas)
    uint64_t selkey[SELCAP];      // 1.6 KB
    uint64_t keys[KPAD];          // 70.1 KB
    uint64_t vmask[2][64];        // 1 KB, double-buffered victim masks
    unsigned long long supW[2][NW];  // per-wave ext-suppression ballots
    int hist[NBIN];               // 8 KB
    int binstart[NBIN];           // 8 KB
    int wavetot[NW];
    int Mshare, nselshare, prevNshare, doneflag;
};  // ~93 KB

// IoU(>0.45) with precomputed areas; explicit RN ops + exact double compare
// match the host fp32 reference bit-for-bit.
__device__ __forceinline__ int iou_sup(float4 a, float aA, float4 b, float bA) {
    float x1 = fmaxf(a.x, b.x), y1 = fmaxf(a.y, b.y);
    float x2 = fminf(a.z, b.z), y2 = fminf(a.w, b.w);
    float iw = fmaxf(__fsub_rn(x2, x1), 0.0f);
    float ih = fmaxf(__fsub_rn(y2, y1), 0.0f);
    float inter = __fmul_rn(iw, ih);
    float uni = __fsub_rn(__fadd_rn(aA, bA), inter);
    return (uni > 0.0f) & ((double)inter > MIDD * (double)uni);
}

__device__ __forceinline__ float4 load_box(const float* __restrict__ img,
                                           int boxoff, uint64_t key) {
    if ((key >> 32) == 0) return make_float4(0.f, 0.f, 0.f, 0.f);
    uint32_t i = 0xFFFFFFFFu - (uint32_t)key;
    const float* bp = img + (size_t)i * LASTD + boxoff;
    return make_float4(bp[0], bp[1], bp[2], bp[3]);
}

__device__ __forceinline__ float box_area(float4 b) {
    return __fmul_rn(__fsub_rn(b.z, b.x), __fsub_rn(b.w, b.y));
}

// Victim masks for one 64-candidate batch: vmask[t] = ballot of lanes L with
// t<L and IoU(t,L)>0.45 (valid L). Wave w owns t in {w, w+16, w+32, w+48}.
__device__ __forceinline__ void compute_vmask(SM* sm, int pp, float4 box,
                                              float a, bool valid, int wav,
                                              int lane) {
    #pragma unroll
    for (int tt = 0; tt < 4; ++tt) {
        int t = wav + tt * NW;
        float4 tb;
        tb.x = __shfl(box.x, t); tb.y = __shfl(box.y, t);
        tb.z = __shfl(box.z, t); tb.w = __shfl(box.w, t);
        float ta = __shfl(a, t);
        unsigned long long vm =
            __ballot(valid && t < lane && iou_sup(box, a, tb, ta));
        if (lane == t) sm->vmask[pp][t] = vm;
    }
}

// One block per (image, class): 2048-bin counting sort of all conf>0.5
// candidates into exact (score desc, idx asc) order, then a split-wave
// pipelined greedy scan (wave0 resolves batch i while waves 1-15 ext-check
// batch i+1), exactly replicating the reference's argmax+suppress loop.
// Scan stops at SELCAP=200 accepts: within-class rank >= 200 can never enter
// the global top-200 (its own class has 200 better-or-equal-and-earlier rows),
// and the zero-fill case only occurs when no class reached 200 — so the cap
// is exactly output-equivalent to the reference's 400.
__global__ __launch_bounds__(THREADS) void nms_per_class(const float* __restrict__ yp,
                                                         float* __restrict__ rows) {
    __shared__ SM sm;
    const int task = blockIdx.x;
    const int b = task / NCM1;
    const int cm1 = task % NCM1;
    const int tid = threadIdx.x;
    const int lane = tid & 63;
    const int wav = tid >> 6;
    const float* img = yp + (size_t)b * NBOX * LASTD;
    const int boxoff = NCL + 4 * cm1;

    // ---- phase 1: conf column loads (all 9 in flight) ----
    float confs[NIT];
    #pragma unroll
    for (int it = 0; it < NIT; ++it) {
        int idx = it * THREADS + tid;
        confs[it] = (idx < NBOX) ? img[(size_t)idx * LASTD + (1 + cm1)] : 0.0f;
    }
    sm.hist[tid] = 0; sm.hist[tid + THREADS] = 0;
    if (tid < 2 * NW) ((unsigned long long*)sm.supW)[tid] = 0ull;
    __syncthreads();

    // ---- phase 2: 2048-bin histogram (top 11 mantissa bits, conf in (0.5,1)) --
    #pragma unroll
    for (int it = 0; it < NIT; ++it) {
        int idx = it * THREADS + tid;
        if (idx < NBOX && confs[it] > CONF_TH) {
            int bin = (int)((__float_as_uint(confs[it]) - 0x3F000000u) >> 12);
            atomicAdd(&sm.hist[bin], 1);
        }
    }
    __syncthreads();

    // ---- phase 3: descending bin bases via suffix-sum over bin pairs ----
    int h0 = sm.hist[2 * tid], h1 = sm.hist[2 * tid + 1];
    int x = h0 + h1;
    int s = x;
    #pragma unroll
    for (int d = 1; d <= 32; d <<= 1) {
        int y = __shfl_down(s, d);
        if (lane + d < 64) s += y;
    }
    if (lane == 0) sm.wavetot[wav] = s;
    __syncthreads();
    int cross = 0;
    #pragma unroll
    for (int w = 0; w < NW; ++w)
        if (w > wav) cross += sm.wavetot[w];
    int Safter = cross + s - x;               // keys in bins strictly above
    sm.binstart[2 * tid + 1] = Safter;        // higher bin (higher score) first
    sm.binstart[2 * tid] = Safter + h1;
    if (tid == 0) sm.Mshare = cross + s;
    sm.hist[2 * tid] = 0; sm.hist[2 * tid + 1] = 0;  // reuse as scatter ctr
    __syncthreads();

    // ---- phase 4: scatter keys to bin regions ----
    #pragma unroll
    for (int it = 0; it < NIT; ++it) {
        int idx = it * THREADS + tid;
        if (idx < NBOX && confs[it] > CONF_TH) {
            uint32_t bits = __float_as_uint(confs[it]);
            int bin = (int)((bits - 0x3F000000u) >> 12);
            int slot = sm.binstart[bin] + atomicAdd(&sm.hist[bin], 1);
            sm.keys[slot] = ((uint64_t)bits << 32) |
                            (uint32_t)(0xFFFFFFFFu - (uint32_t)idx);
        }
    }
    __syncthreads();
    const int M = sm.Mshare;
    for (int m = M + tid; m < KPAD; m += THREADS) sm.keys[m] = 0;
    // ---- phase 5: per-bin insertion sort (2 bins/thread, ~2 keys/bin) ----
    for (int f = tid; f < NBIN; f += THREADS) {
        int s0 = sm.binstart[f], h = sm.hist[f];
        for (int i2 = 1; i2 < h; ++i2) {
            uint64_t key = sm.keys[s0 + i2];
            int j = i2 - 1;
            while (j >= 0 && sm.keys[s0 + j] < key) {
                sm.keys[s0 + j + 1] = sm.keys[s0 + j];
                --j;
            }
            sm.keys[s0 + j + 1] = key;
        }
    }
    __syncthreads();

    // ---- phase 6: split-wave pipelined greedy scan ----
    // Parity p = i&1. Entering iter i: supW[p] holds cur's ext-ballots vs
    // accepted[0..prevN) (from full-check at iter i-1); vmask[p] holds cur's
    // intra-batch victim masks. Delta-check covers [prevN..nsel). Resolve(cur)
    // on wave0 overlaps full ext-check of nxt vs [0..nselPre) on waves 1-15.
    uint64_t keyC = sm.keys[lane];
    uint64_t keyN = sm.keys[64 + lane];
    float4 boxC = load_box(img, boxoff, keyC);
    float4 boxN = load_box(img, boxoff, keyN);
    float aC = box_area(boxC), aN = box_area(boxN);
    compute_vmask(&sm, 0, boxC, aC, (keyC >> 32) != 0, wav, lane);

    int nsel = 0, prevN = 0;
    bool done = false;
    for (int i = 0; i < NBATCH && !done; ++i) {
        const int p = i & 1;
        const bool vC = (keyC >> 32) != 0;
        const bool vN = (keyN >> 32) != 0;
        // A: delta ext-check of cur vs newly accepted [prevN, nsel)
        {
            int sup = 0;
            for (int j = prevN + wav; j < nsel; j += NW)
                sup |= iou_sup(boxC, aC, sm.selbox[j], sm.selA[j]);
            unsigned long long bal = __ballot(vC && sup);
            if (lane == 0 && bal) atomicOr(&sm.supW[p][wav], bal);
        }
        // B: victim masks for nxt -> other parity buffer
        compute_vmask(&sm, p ^ 1, boxN, aN, vN, wav, lane);
        // C: prefetch batch i+2
        int f0 = (i + 2) * 64;
        uint64_t key2 = (f0 < KPAD) ? sm.keys[f0 + lane] : 0;
        float4 box2 = load_box(img, boxoff, key2);
        float a2 = box_area(box2);
        __syncthreads();  // [1] supW[p], vmask[p^1] final; snapshot nsel
        const int nselPre = nsel;
        if (wav == 0) {
            // resolve cur: sequential greedy over 64 candidates
            unsigned long long V = __ballot(vC);
            unsigned long long E = (lane < NW) ? sm.supW[p][lane] : 0ull;
            #pragma unroll
            for (int d = 1; d < NW; d <<= 1) E |= __shfl_xor(E, d);
            E = __shfl(E, 0);
            if (lane < NW) sm.supW[p][lane] = 0ull;   // recycle for batch i+2
            uint64_t vm = sm.vmask[p][lane];
            uint64_t alive = ~(E | ~V);
            uint64_t accm = 0;
            int cnt = nsel;
            while (alive && cnt < SELCAP) {
                int t = __ffsll((unsigned long long)alive) - 1;
                accm |= 1ull << t;
                cnt++;
                uint64_t vt = (uint64_t)__shfl((unsigned long long)vm, t);
                alive &= ~vt;
                alive &= ~(1ull << t);
            }
            if ((accm >> lane) & 1ull) {
                int pos = nsel + __popcll(accm & ((1ull << lane) - 1ull));
                sm.selbox[pos] = boxC;
                sm.selA[pos] = aC;
                sm.selkey[pos] = keyC;
            }
            if (lane == 0) {
                sm.nselshare = cnt;
                sm.prevNshare = nselPre;
                sm.doneflag = (cnt >= SELCAP) || (V != ~0ull);
            }
        } else {
            // full ext-check of nxt vs accepted snapshot [0..nselPre)
            int supN = 0;
            for (int j = wav - 1; j < nselPre; j += NW - 1)
                supN |= iou_sup(boxN, aN, sm.selbox[j], sm.selA[j]);
            unsigned long long balN = __ballot(vN && supN);
            if (lane == 0 && balN) atomicOr(&sm.supW[p ^ 1][wav], balN);
        }
        __syncthreads();  // [2] accepts + counters published
        nsel = sm.nselshare;
        prevN = sm.prevNshare;
        done = sm.doneflag != 0;
        keyC = keyN; boxC = boxN; aC = aN;
        keyN = key2; boxN = box2; aN = a2;
    }

    // ---- phase 7: emit ranks [0,256) (all topk reads); zeros past nsel ----
    float* out0 = rows + (size_t)task * MAXOUT * 7;
    for (int r = tid; r < EMITN; r += THREADS) {
        float* o = out0 + (size_t)r * 7;
        if (r < nsel) {
            uint64_t key = sm.selkey[r];
            uint32_t i = 0xFFFFFFFFu - (uint32_t)key;
            float4 bx = sm.selbox[r];
            o[0] = (float)(cm1 + 1);
            o[1] = __uint_as_float((uint32_t)(key >> 32));
            o[2] = bx.x;
            o[3] = bx.y;
            o[4] = bx.z;
            o[5] = bx.w;
            o[6] = img[(size_t)i * LASTD + (LASTD - 1)];
        } else {
            #pragma unroll
            for (int q = 0; q < 7; ++q) o[q] = 0.0f;
        }
    }
}

// One block per image: top-200 by (conf desc, flat idx asc) over 20*400 rows.
// Per-class lists are already sorted desc; top-200 never needs within-class
// rank >= 256, so: 32 lists x 256 keys, 5 rounds of pairwise bitonic top-256
// merges (max-combine + 8 merge stages), then gather the first 200 rows.
// Flat index keeps the reference's list*400+r encoding for exact tie order.
__global__ __launch_bounds__(THREADS) void topk_per_image(const float* __restrict__ rows,
                                                          float* __restrict__ out) {
    __shared__ uint64_t K[8192];
    const int b = blockIdx.x;
    const int tid = threadIdx.x;
    const float* rb = rows + (size_t)b * (NCM1 * MAXOUT) * 7;

    for (int xx = tid; xx < 8192; xx += THREADS) {
        int list = xx >> 8, r = xx & 255;
        uint64_t k = 0;
        if (list < NCM1) {
            int flat = list * MAXOUT + r;
            float conf = rb[(size_t)flat * 7 + 1];
            k = ((uint64_t)__float_as_uint(conf) << 32) |
                (uint32_t)(0xFFFFFFFFu - (uint32_t)flat);
        }
        K[xx] = k;
    }
    __syncthreads();

    for (int round = 0; round < 5; ++round) {
        int npairs = 16 >> round;
        int sep = 256 << round;
        for (int w = tid; w < npairs * 256; w += THREADS) {
            int p = w >> 8, t = w & 255;
            int A = p * 2 * sep;
            uint64_t a = K[A + t];
            uint64_t c = K[A + sep + 255 - t];
            K[A + t] = a > c ? a : c;
        }
        __syncthreads();
        for (int j = 128; j >= 1; j >>= 1) {
            for (int w = tid; w < npairs * 128; w += THREADS) {
                int p = w >> 7, q = w & 127;
                int t = ((q & ~(j - 1)) << 1) | (q & (j - 1));
                int A = p * 2 * sep;
                uint64_t x0 = K[A + t];
                uint64_t x1 = K[A + t + j];
                if (x0 < x1) { K[A + t] = x1; K[A + t + j] = x0; }
            }
            __syncthreads();
        }
    }

    if (tid < TOPK) {
        uint64_t key = K[tid];
        uint32_t flat = 0xFFFFFFFFu - (uint32_t)key;
        const float* src = rb + (size_t)flat * 7;
        float* o = out + ((size_t)b * TOPK + tid) * 7;
        #pragma unroll
        for (int q = 0; q < 7; ++q) o[q] = src[q];
    }
}

extern "C" void kernel_launch(void* const* d_in, const int* in_sizes, int n_in,
                              void* d_out, int out_size, void* d_ws, size_t ws_size,
                              hipStream_t stream) {
    const float* yp = (const float*)d_in[0];
    float* rows = (float*)d_ws;  // NTASK*400*7 floats = 1.792 MB scratch
    float* out = (float*)d_out;

    hipLaunchKernelGGL(nms_per_class, dim3(NTASK), dim3(THREADS), 0, stream, yp, rows);
    hipLaunchKernelGGL(topk_per_image, dim3(NB), dim3(THREADS), 0, stream, rows, out);
}